// Round 1
// baseline (7937.521 us; speedup 1.0000x reference)
//
#include <hip/hip_runtime.h>

// Fsmm_rnn: 2-layer tanh RNN (B=64,T=2048,D=4,H=256) + closed-form last-step grad
// + fractional-memory Up at t=T-1 + (64,64) broadcast assemblies.
//
// Kernel 1: one workgroup per batch (256 thr = 4 waves, 1 wave/SIMD).
//   Thread j holds f16-packed rows j of Whh0, Wih1, Whh1 in VGPRs (384 regs),
//   h state lives in LDS (f16), broadcast-read as uint4. v_dot2_f32_f16 MACs.
// Kernel 2: assemble loss1/loss2 (64x64 each).

#define TT 2048
#define HH 256
#define WIN 64

typedef _Float16 h2 __attribute__((ext_vector_type(2)));

__device__ __forceinline__ float fdot2p(h2 a, h2 b, float c) {
#if __has_builtin(__builtin_amdgcn_fdot2)
  return __builtin_amdgcn_fdot2(a, b, c, false);
#else
  return (float)a.x * (float)b.x + (float)a.y * (float)b.y + c;
#endif
}

__device__ __forceinline__ float tanh_fast(float x) {
  float xc = fminf(fmaxf(x, -15.f), 15.f);
  float e = __expf(2.f * xc);                    // v_exp path
  return (e - 1.f) * __builtin_amdgcn_rcpf(e + 1.f);
}

__device__ __forceinline__ float block_sum(float v, float* red, int tid) {
#pragma unroll
  for (int off = 32; off >= 1; off >>= 1) v += __shfl_down(v, off, 64);
  __syncthreads();                               // protect red reuse
  if ((tid & 63) == 0) red[tid >> 6] = v;
  __syncthreads();
  return red[0] + red[1] + red[2] + red[3];
}

// 256-elem f16 dot: 32x uint4 broadcast reads from LDS, 128 dot2 into 4 accums.
#define DOT32(WARR, PTR, A0, A1, A2, A3)                                   \
  {                                                                        \
    const uint4* _p = (const uint4*)(PTR);                                 \
    _Pragma("unroll") for (int _i = 0; _i < 32; ++_i) {                    \
      uint4 _h = _p[_i];                                                   \
      A0 = fdot2p(WARR[4 * _i + 0], __builtin_bit_cast(h2, _h.x), A0);     \
      A1 = fdot2p(WARR[4 * _i + 1], __builtin_bit_cast(h2, _h.y), A1);     \
      A2 = fdot2p(WARR[4 * _i + 2], __builtin_bit_cast(h2, _h.z), A2);     \
      A3 = fdot2p(WARR[4 * _i + 3], __builtin_bit_cast(h2, _h.w), A3);     \
    }                                                                      \
  }

__global__ __launch_bounds__(256, 1) void rnn_chain_kernel(
    const float* __restrict__ x, const float* __restrict__ Wih0,
    const float* __restrict__ Whh0, const float* __restrict__ bih0,
    const float* __restrict__ bhh0, const float* __restrict__ Wih1,
    const float* __restrict__ Whh1, const float* __restrict__ bih1,
    const float* __restrict__ bhh1, const float* __restrict__ fcW,
    const float* __restrict__ fcb, const float* __restrict__ f1W,
    const float* __restrict__ f1b, const float* __restrict__ f2W,
    const float* __restrict__ f2b, const float* __restrict__ C1,
    const float* __restrict__ R1, const float* __restrict__ binom,
    float* __restrict__ out_soc,  // d_out[0..64)
    float* __restrict__ ws)       // [0..64) d_soc, [64..128) f_soc, [128..192) Up_last
{
  const int b = blockIdx.x;
  const int j = threadIdx.x;

  __shared__ __align__(16) float xs[TT * 4];          // 32 KB: whole x[b] series
  __shared__ __align__(16) _Float16 h0L[2][HH];       // ping-pong h0 (f16)
  __shared__ __align__(16) _Float16 h1L[2][HH];       // ping-pong h1 (f16)
  __shared__ float red[4];
  __shared__ float uL[HH];

  // ---- preload x[b] into LDS (coalesced float4) ----
  const float4* xg = (const float4*)(x + (size_t)b * TT * 4);
  float4* xl = (float4*)xs;
  for (int i = j; i < TT; i += 256) xl[i] = xg[i];

  // ---- load + convert weight rows into registers (f16 packed) ----
  h2 w0[128], w1i[128], w1h[128];
  {
    const float4* g0 = (const float4*)(Whh0 + (size_t)j * HH);
#pragma unroll
    for (int i = 0; i < 64; ++i) {
      float4 a = g0[i];
      h2 t0; t0.x = (_Float16)a.x; t0.y = (_Float16)a.y; w0[2 * i] = t0;
      h2 t1; t1.x = (_Float16)a.z; t1.y = (_Float16)a.w; w0[2 * i + 1] = t1;
      __builtin_amdgcn_sched_barrier(0);   // cap load batching -> no reg spike
    }
    const float4* g1 = (const float4*)(Wih1 + (size_t)j * HH);
#pragma unroll
    for (int i = 0; i < 64; ++i) {
      float4 a = g1[i];
      h2 t0; t0.x = (_Float16)a.x; t0.y = (_Float16)a.y; w1i[2 * i] = t0;
      h2 t1; t1.x = (_Float16)a.z; t1.y = (_Float16)a.w; w1i[2 * i + 1] = t1;
      __builtin_amdgcn_sched_barrier(0);
    }
    const float4* g2 = (const float4*)(Whh1 + (size_t)j * HH);
#pragma unroll
    for (int i = 0; i < 64; ++i) {
      float4 a = g2[i];
      h2 t0; t0.x = (_Float16)a.x; t0.y = (_Float16)a.y; w1h[2 * i] = t0;
      h2 t1; t1.x = (_Float16)a.z; t1.y = (_Float16)a.w; w1h[2 * i + 1] = t1;
      __builtin_amdgcn_sched_barrier(0);
    }
  }
  const float wx0 = Wih0[j * 4 + 0], wx1 = Wih0[j * 4 + 1];
  const float wx2 = Wih0[j * 4 + 2], wx3 = Wih0[j * 4 + 3];
  const float bias0 = bih0[j] + bhh0[j];
  const float bias1 = bih1[j] + bhh1[j];

  h0L[0][j] = (_Float16)0.f;
  h1L[0][j] = (_Float16)0.f;
  __syncthreads();

  // ---- sequential scan, 2 barriers/step ----
  int p = 0;
  float h0n = 0.f, h1n = 0.f;
  for (int t = 0; t < TT; ++t) {
    float4 xt = xl[t];  // uniform broadcast
    // phase A: h0_new = tanh(Wih0 x_t + Whh0 h0_prev + b); also Whh1 h1_prev
    float a0 = 0, a1 = 0, a2 = 0, a3 = 0;
    float c0 = 0, c1 = 0, c2 = 0, c3 = 0;
    DOT32(w0, &h0L[p][0], a0, a1, a2, a3);
    DOT32(w1h, &h1L[p][0], c0, c1, c2, c3);
    float z0 = ((a0 + a1) + (a2 + a3)) + wx0 * xt.x + wx1 * xt.y +
               wx2 * xt.z + wx3 * xt.w + bias0;
    h0n = tanh_fast(z0);
    float acc1h = (c0 + c1) + (c2 + c3);
    h0L[p ^ 1][j] = (_Float16)h0n;
    __syncthreads();
    // phase B: h1_new = tanh(Wih1 h0_new + Whh1 h1_prev + b)
    float e0 = 0, e1 = 0, e2 = 0, e3 = 0;
    DOT32(w1i, &h0L[p ^ 1][0], e0, e1, e2, e3);
    float z1 = ((e0 + e1) + (e2 + e3)) + acc1h + bias1;
    h1n = tanh_fast(z1);
    h1L[p ^ 1][j] = (_Float16)h1n;
    __syncthreads();
    p ^= 1;
  }

  // ---- epilogue: soc, f_soc, d_soc, Up_last (all per batch) ----
  const float h0T = h0n;  // ys1[T-1][j], f32 lane-local
  const float h1T = h1n;  // hT[j]
  const float fw = fcW[j];

  float socb = block_sum(fw * h1T, red, j) + fcb[0];
  if (j == 0) out_soc[b] = socb;

  float fsb = block_sum(f2W[j] * (socb * f1W[j] + f1b[j]), red, j) + f2b[0];
  if (j == 0) ws[64 + b] = fsb;

  // d_soc: g[h] = sum_k fcW[k](1-hT[k]^2) Wih1[k,h]; then dot with
  //        (1-h0T[h]^2) * Wih0[h,3]
  uL[j] = fw * (1.f - h1T * h1T);
  __syncthreads();
  float g = 0.f;
#pragma unroll 8
  for (int k = 0; k < HH; ++k) g += uL[k] * Wih1[(size_t)k * HH + j];
  float dsoc = block_sum(g * (1.f - h0T * h0T) * wx3, red, j);
  if (j == 0) ws[b] = dsoc;

  // Up[:, -1]: Ts = sqrt((time[T-1]-time[T-64])/63); hist = sum binom[j+1]*v[1984+j]
  float histv = 0.f;
  if (j < WIN) histv = binom[j + 1] * xs[(TT - WIN + j) * 4 + 0];
  float hist = block_sum(histv, red, j);
  if (j == 0) {
    float tl = xs[(TT - 1) * 4 + 3], t0v = xs[(TT - WIN) * 4 + 3];
    float tdiff = (tl - t0v) * (1.0f / (float)(WIN - 1));
    float Ts = sqrtf(tdiff);  // tdiff**0.5 (valid=64>1 always since T>WINDOW)
    float vlast = xs[(TT - 1) * 4 + 0], Ilast = xs[(TT - 1) * 4 + 1];
    float r1 = R1[0], c1v = C1[0];
    float up = -Ts / (r1 * c1v) * vlast + Ts / c1v * Ilast - hist;
    ws[128 + b] = up;
  }
}

__global__ void assemble_kernel(const float* __restrict__ x,
                                const float* __restrict__ Q,
                                const float* __restrict__ delta,
                                const float* __restrict__ R0,
                                const float* __restrict__ ws,
                                float* __restrict__ out) {
  const int i = blockIdx.x;    // row (batch)
  const int jj = threadIdx.x;  // col 0..63
  const float dq = delta[0] / Q[0];
  const size_t base = ((size_t)i * TT + (TT - 1)) * 4;
  const float xv0 = x[base + 0];
  const float xv1 = x[base + 1];
  const float fs = ws[64 + i];
  // loss1[i,j] = delta/Q * x[i,-1,1] + d_soc[j]
  out[64 + i * 64 + jj] = dq * xv1 + ws[jj];
  // loss2[i,j] = f_soc[i] - x[i,-1,0] - R0*x[i,-1,1] - Up_last[j]
  out[64 + 4096 + i * 64 + jj] = fs - xv0 - R0[0] * xv1 - ws[128 + jj];
}

extern "C" void kernel_launch(void* const* d_in, const int* in_sizes, int n_in,
                              void* d_out, int out_size, void* d_ws,
                              size_t ws_size, hipStream_t stream) {
  const float* x    = (const float*)d_in[0];
  const float* Wih0 = (const float*)d_in[1];
  const float* Whh0 = (const float*)d_in[2];
  const float* bih0 = (const float*)d_in[3];
  const float* bhh0 = (const float*)d_in[4];
  const float* Wih1 = (const float*)d_in[5];
  const float* Whh1 = (const float*)d_in[6];
  const float* bih1 = (const float*)d_in[7];
  const float* bhh1 = (const float*)d_in[8];
  const float* fcW  = (const float*)d_in[9];
  const float* fcb  = (const float*)d_in[10];
  const float* Q    = (const float*)d_in[11];
  const float* delta= (const float*)d_in[12];
  const float* f1W  = (const float*)d_in[13];
  const float* f1b  = (const float*)d_in[14];
  const float* f2W  = (const float*)d_in[15];
  const float* f2b  = (const float*)d_in[16];
  // d_in[17] = U0 (unused by reference)
  const float* R0   = (const float*)d_in[18];
  const float* C1   = (const float*)d_in[19];
  const float* R1   = (const float*)d_in[20];
  const float* binom= (const float*)d_in[21];

  float* out = (float*)d_out;
  float* ws  = (float*)d_ws;

  hipLaunchKernelGGL(rnn_chain_kernel, dim3(64), dim3(256), 0, stream, x, Wih0,
                     Whh0, bih0, bhh0, Wih1, Whh1, bih1, bhh1, fcW, fcb, f1W,
                     f1b, f2W, f2b, C1, R1, binom, out, ws);
  hipLaunchKernelGGL(assemble_kernel, dim3(64), dim3(64), 0, stream, x, Q,
                     delta, R0, ws, out);
}